// Round 1
// baseline (652.191 us; speedup 1.0000x reference)
//
#include <hip/hip_runtime.h>

#define S_DIM 512
#define C_DIM 128
#define SS (S_DIM*S_DIM)          // 262144 rows
#define LN_EPS 1e-5f

typedef unsigned short u16;
typedef unsigned int   u32;

typedef __bf16 bf16x8 __attribute__((ext_vector_type(8)));
typedef float  f32x4  __attribute__((ext_vector_type(4)));

struct alignas(16) V16  { u32 x, y, z, w; };   // 16B chunk
struct U16_8 { u16 v[8]; };
struct alignas(8) U16_4 { u16 v[4]; };
struct alignas(16) F4   { float x, y, z, w; };

__device__ inline u16 f2bf(float f) {          // RNE float->bf16
    u32 u = __float_as_uint(f);
    u32 r = u + 0x7fffu + ((u >> 16) & 1u);
    return (u16)(r >> 16);
}
__device__ inline float bf2f(u16 s) {
    return __uint_as_float(((u32)s) << 16);
}

// ---------------- K0: weights fp32 -> bf16 (Wabg packed [384][128], Wf [128][128])
__global__ __launch_bounds__(256) void k0_prep(
    const float* __restrict__ Wa, const float* __restrict__ Wb, const float* __restrict__ Wg,
    const float* __restrict__ Wf, u16* __restrict__ Wabg, u16* __restrict__ Wfb)
{
    int idx = blockIdx.x * 256 + threadIdx.x;   // 0..65535
    if      (idx < 16384) Wabg[idx]         = f2bf(Wa[idx]);
    else if (idx < 32768) Wabg[idx]         = f2bf(Wb[idx - 16384]);
    else if (idx < 49152) Wabg[idx]         = f2bf(Wg[idx - 32768]);
    else                  Wfb[idx - 49152]  = f2bf(Wf[idx - 49152]);
}

// ---------------- K1: LN1 + 3 projections + sigmoid.
// Outputs: aT channel-major [c][r] (r = i*512+k), b_rm row-major [r][c], g_rm row-major [r][c].
__global__ __launch_bounds__(256) void k1_ln_proj(
    const float* __restrict__ z, const float* __restrict__ ln1w, const float* __restrict__ ln1b,
    const u16* __restrict__ Wabg,
    u16* __restrict__ aT, u16* __restrict__ b_rm, u16* __restrict__ g_rm)
{
    __shared__ float zt[64][132];   // +4 pad: bank-spread for LN reads
    __shared__ u16   zn[64][128];   // bf16, chunk-XOR swizzled for MFMA A-frag reads
    const int t  = threadIdx.x;
    const int r0 = blockIdx.x * 64;

    // load z tile [64][128] fp32, coalesced float4
    #pragma unroll
    for (int it = 0; it < 8; ++it) {
        int idx = it*256 + t;
        int row = idx >> 5, c4 = idx & 31;
        F4 v = *(const F4*)(z + (size_t)(r0 + row)*C_DIM + c4*4);
        *(F4*)&zt[row][c4*4] = v;
    }
    __syncthreads();

    // LayerNorm: 4 threads per row
    {
        int row = t >> 2, part = t & 3;
        float vals[32];
        float s = 0.f, sq = 0.f;
        #pragma unroll
        for (int c4 = 0; c4 < 8; ++c4) {
            F4 v = *(const F4*)&zt[row][part*32 + c4*4];
            vals[c4*4+0]=v.x; vals[c4*4+1]=v.y; vals[c4*4+2]=v.z; vals[c4*4+3]=v.w;
            s  += v.x + v.y + v.z + v.w;
            sq += v.x*v.x + v.y*v.y + v.z*v.z + v.w*v.w;
        }
        s += __shfl_xor(s,1); sq += __shfl_xor(sq,1);
        s += __shfl_xor(s,2); sq += __shfl_xor(sq,2);
        float mean = s * (1.f/128.f);
        float var  = sq * (1.f/128.f) - mean*mean;
        float rstd = rsqrtf(var + LN_EPS);
        #pragma unroll
        for (int qq = 0; qq < 4; ++qq) {
            int q = part*4 + qq;               // logical 8-elem chunk (of 16)
            U16_8 pk;
            #pragma unroll
            for (int e = 0; e < 8; ++e) {
                int c = q*8 + e;
                float nv = (vals[qq*8+e] - mean) * rstd * ln1w[c] + ln1b[c];
                pk.v[e] = f2bf(nv);
            }
            int p = q ^ (row & 15);            // XOR swizzle (T2-style)
            *(V16*)&zn[row][p*8] = __builtin_bit_cast(V16, pk);
        }
    }
    __syncthreads();

    // MFMA: wave w -> 16 rows, all 384 output cols (Wa|Wb|Wg)
    {
        const int w  = t >> 6;
        const int l  = t & 63;
        const int lr = l & 15;    // A row / B col / D col
        const int lg = l >> 4;    // k-group
        bf16x8 afrag[4];
        #pragma unroll
        for (int ks = 0; ks < 4; ++ks) {       // K=128 -> 4 MFMA k-steps
            int p = (ks*4 + lg) ^ lr;
            afrag[ks] = __builtin_bit_cast(bf16x8, *(const V16*)&zn[w*16 + lr][p*8]);
        }
        const int rb = r0 + w*16 + 4*lg;       // D-frag row base (ri 0..3)
        for (int ct = 0; ct < 24; ++ct) {
            f32x4 acc = {0.f, 0.f, 0.f, 0.f};
            #pragma unroll
            for (int ks = 0; ks < 4; ++ks) {
                V16 ld = *(const V16*)(Wabg + ((ct*16 + lr)*C_DIM + ks*32 + lg*8));
                acc = __builtin_amdgcn_mfma_f32_16x16x32_bf16(
                        afrag[ks], __builtin_bit_cast(bf16x8, ld), acc, 0, 0, 0);
            }
            u16 sv[4];
            #pragma unroll
            for (int ri = 0; ri < 4; ++ri)
                sv[ri] = f2bf(1.f / (1.f + __expf(-acc[ri])));
            if (ct < 8) {                      // a: channel-major, 4 consecutive r -> 8B store
                int d = ct*16 + lr;
                U16_4 pk; pk.v[0]=sv[0]; pk.v[1]=sv[1]; pk.v[2]=sv[2]; pk.v[3]=sv[3];
                *(U16_4*)(aT + (size_t)d*SS + rb) = pk;
            } else if (ct < 16) {              // b: row-major
                int d = (ct-8)*16 + lr;
                #pragma unroll
                for (int ri = 0; ri < 4; ++ri)
                    b_rm[(size_t)(rb + ri)*C_DIM + d] = sv[ri];
            } else {                           // g: row-major
                int d = (ct-16)*16 + lr;
                #pragma unroll
                for (int ri = 0; ri < 4; ++ri)
                    g_rm[(size_t)(rb + ri)*C_DIM + d] = sv[ri];
            }
        }
    }
}

// ---------------- K2: permute b[k][j][c] -> bT[c][j][k]  (tile: k32 x j8 x c64)
__global__ __launch_bounds__(256) void k2_transpose_b(
    const u16* __restrict__ b_rm, u16* __restrict__ bT)
{
    __shared__ u16 T[64*8*40];                 // [c][j][k pad 32->40]
    const int t  = threadIdx.x;
    const int k0 = blockIdx.x * 32;
    const int j0 = blockIdx.y * 8;
    const int c0 = blockIdx.z * 64;
    #pragma unroll
    for (int it = 0; it < 8; ++it) {
        int ch = it*256 + t;                   // 0..2047 16B chunks
        int rl = ch >> 3, cc = ch & 7;
        int k = rl >> 3, j = rl & 7;
        V16 ld = *(const V16*)(b_rm + (size_t)((k0+k)*S_DIM + (j0+j))*C_DIM + c0 + cc*8);
        U16_8 u = __builtin_bit_cast(U16_8, ld);
        #pragma unroll
        for (int e = 0; e < 8; ++e)
            T[(cc*8+e)*320 + j*40 + k] = u.v[e];
    }
    __syncthreads();
    #pragma unroll
    for (int it = 0; it < 8; ++it) {
        int idx = it*256 + t;                  // 0..2047 16B out-chunks
        int half = idx & 3, j = (idx>>2) & 7, cl = idx >> 5;
        V16 v = *(const V16*)&T[cl*320 + j*40 + half*8];
        *(V16*)(bT + (size_t)(c0+cl)*SS + (size_t)(j0+j)*S_DIM + k0 + half*8) = v;
    }
}

// ---------------- K3: 128 batched NT GEMMs: sum[i][j] = A[i][:]·B[j][:]^T per channel.
// 128x128 tile, BK=64, 4 waves (2x2), XOR-swizzled LDS, stores (sum-128) as bf16 to sumT[c][i][j].
__global__ __launch_bounds__(256) void k3_gemm(
    const u16* __restrict__ aT, const u16* __restrict__ bT, u16* __restrict__ sumT)
{
    __shared__ u16 At[128*64];
    __shared__ u16 Bt[128*64];
    const int t = threadIdx.x;
    // XCD-chunked swizzle: each XCD gets 16 contiguous channels (panels stay in its L2)
    int lid  = blockIdx.x;                     // 0..2047
    int work = (lid & 7) * 256 + (lid >> 3);
    int c    = work >> 4;
    int tile = work & 15;
    int i0 = (tile >> 2) * 128;
    int j0 = (tile & 3) * 128;
    const u16* Ac = aT + (size_t)c*SS;
    const u16* Bc = bT + (size_t)c*SS;
    const int w = t>>6, l = t&63, lr = l&15, lg = l>>4;
    const int wr = w>>1, wc = w&1;
    f32x4 acc[4][4];
    #pragma unroll
    for (int m = 0; m < 4; ++m)
        #pragma unroll
        for (int n = 0; n < 4; ++n)
            acc[m][n] = (f32x4){0.f,0.f,0.f,0.f};

    for (int kk = 0; kk < 8; ++kk) {
        __syncthreads();
        int k0 = kk*64;
        #pragma unroll
        for (int it = 0; it < 4; ++it) {       // reg-staged, swizzled LDS writes
            int s = it*256 + t;
            int row = s >> 3, q = s & 7;
            int p = q ^ (row & 7);
            V16 va = *(const V16*)(Ac + (size_t)(i0+row)*S_DIM + k0 + q*8);
            *(V16*)&At[row*64 + p*8] = va;
            V16 vb = *(const V16*)(Bc + (size_t)(j0+row)*S_DIM + k0 + q*8);
            *(V16*)&Bt[row*64 + p*8] = vb;
        }
        __syncthreads();
        #pragma unroll
        for (int ks = 0; ks < 2; ++ks) {
            bf16x8 af[4], bfr[4];
            #pragma unroll
            for (int m = 0; m < 4; ++m) {
                int row = wr*64 + m*16 + lr;
                int p = (ks*4 + lg) ^ (row & 7);
                af[m] = __builtin_bit_cast(bf16x8, *(const V16*)&At[row*64 + p*8]);
            }
            #pragma unroll
            for (int n = 0; n < 4; ++n) {
                int row = wc*64 + n*16 + lr;
                int p = (ks*4 + lg) ^ (row & 7);
                bfr[n] = __builtin_bit_cast(bf16x8, *(const V16*)&Bt[row*64 + p*8]);
            }
            #pragma unroll
            for (int m = 0; m < 4; ++m)
                #pragma unroll
                for (int n = 0; n < 4; ++n)
                    acc[m][n] = __builtin_amdgcn_mfma_f32_16x16x32_bf16(af[m], bfr[n], acc[m][n], 0,0,0);
        }
    }
    #pragma unroll
    for (int m = 0; m < 4; ++m) {
        int ib = i0 + wr*64 + m*16 + 4*lg;
        #pragma unroll
        for (int n = 0; n < 4; ++n) {
            int jb = j0 + wc*64 + n*16 + lr;
            #pragma unroll
            for (int ri = 0; ri < 4; ++ri)
                sumT[(size_t)c*SS + (size_t)(ib+ri)*S_DIM + jb] = f2bf(acc[m][n][ri] - 128.f);
        }
    }
}

// ---------------- K4: gather sumT, LN2, Wf projection, *g, fp32 out
__global__ __launch_bounds__(256) void k4_out(
    const u16* __restrict__ sumT, const u16* __restrict__ g_rm, const u16* __restrict__ Wfb,
    const float* __restrict__ ln2w, const float* __restrict__ ln2b,
    float* __restrict__ out)
{
    __shared__ u16 st[128*64];   // [c][r_local]
    __shared__ u16 gt[64*128];   // [r_local][d]
    __shared__ u16 zn[64*128];   // [r_local][c] swizzled
    const int t  = threadIdx.x;
    const int r0 = blockIdx.x * 64;
    #pragma unroll
    for (int it = 0; it < 4; ++it) {
        int s = it*256 + t;
        int cch = s >> 3, rc = s & 7;
        V16 v = *(const V16*)(sumT + (size_t)cch*SS + r0 + rc*8);
        *(V16*)&st[cch*64 + rc*8] = v;
    }
    #pragma unroll
    for (int it = 0; it < 4; ++it) {
        int s = it*256 + t;
        int row = s >> 4, cc = s & 15;
        V16 v = *(const V16*)(g_rm + (size_t)(r0+row)*C_DIM + cc*8);
        *(V16*)&gt[row*128 + cc*8] = v;
    }
    __syncthreads();
    {
        int row = t >> 2, part = t & 3;
        float vals[32];
        float s = 0.f, sq = 0.f;
        #pragma unroll
        for (int ci = 0; ci < 32; ++ci) {
            float x = bf2f(st[(part*32 + ci)*64 + row]);
            vals[ci] = x; s += x; sq += x*x;
        }
        s += __shfl_xor(s,1); sq += __shfl_xor(sq,1);
        s += __shfl_xor(s,2); sq += __shfl_xor(sq,2);
        float mean = s * (1.f/128.f);
        float var  = sq * (1.f/128.f) - mean*mean;   // shift-invariant (stored = sum-128)
        float rstd = rsqrtf(var + LN_EPS);
        #pragma unroll
        for (int qq = 0; qq < 4; ++qq) {
            int q = part*4 + qq;
            U16_8 pk;
            #pragma unroll
            for (int e = 0; e < 8; ++e) {
                int c = q*8 + e;
                float nv = (vals[qq*8+e] - mean) * rstd * ln2w[c] + ln2b[c];
                pk.v[e] = f2bf(nv);
            }
            int p = q ^ (row & 15);
            *(V16*)&zn[row*128 + p*8] = __builtin_bit_cast(V16, pk);
        }
    }
    __syncthreads();
    {
        const int w = t>>6, l = t&63, lr = l&15, lg = l>>4;
        bf16x8 afrag[4];
        #pragma unroll
        for (int ks = 0; ks < 4; ++ks) {
            int p = (ks*4 + lg) ^ lr;
            afrag[ks] = __builtin_bit_cast(bf16x8, *(const V16*)&zn[(w*16 + lr)*128 + p*8]);
        }
        const int rbl = w*16 + 4*lg;
        #pragma unroll
        for (int ct = 0; ct < 8; ++ct) {
            f32x4 acc = {0.f,0.f,0.f,0.f};
            #pragma unroll
            for (int ks = 0; ks < 4; ++ks) {
                V16 ld = *(const V16*)(Wfb + ((ct*16 + lr)*C_DIM + ks*32 + lg*8));
                acc = __builtin_amdgcn_mfma_f32_16x16x32_bf16(
                        afrag[ks], __builtin_bit_cast(bf16x8, ld), acc, 0,0,0);
            }
            #pragma unroll
            for (int ri = 0; ri < 4; ++ri) {
                float gv = bf2f(gt[(rbl + ri)*128 + ct*16 + lr]);
                out[(size_t)(r0 + rbl + ri)*C_DIM + ct*16 + lr] = gv * acc[ri];
            }
        }
    }
}

extern "C" void kernel_launch(void* const* d_in, const int* in_sizes, int n_in,
                              void* d_out, int out_size, void* d_ws, size_t ws_size,
                              hipStream_t stream)
{
    (void)in_sizes; (void)n_in; (void)out_size; (void)ws_size;
    const float* z    = (const float*)d_in[0];
    const float* ln1w = (const float*)d_in[1];
    const float* ln1b = (const float*)d_in[2];
    const float* Wa   = (const float*)d_in[3];
    const float* Wb   = (const float*)d_in[4];
    const float* Wg   = (const float*)d_in[5];
    const float* ln2w = (const float*)d_in[6];
    const float* ln2b = (const float*)d_in[7];
    const float* Wf   = (const float*)d_in[8];

    // ws layout: Wabg(96K) | Wf(32K) | aT(64Mi) | g(64Mi) | sumT(64Mi)  => ~201.4 MB
    u16* Wabg = (u16*)d_ws;
    u16* Wfb  = Wabg + 384*128;
    u16* big  = (u16*)((char*)d_ws + (128u << 10));
    u16* aT   = big;
    u16* g_rm = big + ((size_t)1 << 25);
    u16* sumT = big + ((size_t)2 << 25);
    // d_out doubles as scratch for b (row-major) and bT; K4 overwrites it last.
    u16* b_rm = (u16*)d_out;
    u16* bT   = b_rm + ((size_t)1 << 25);
    float* out = (float*)d_out;

    k0_prep     <<<256, 256, 0, stream>>>(Wa, Wb, Wg, Wf, Wabg, Wfb);
    k1_ln_proj  <<<4096, 256, 0, stream>>>(z, ln1w, ln1b, Wabg, aT, b_rm, g_rm);
    k2_transpose_b<<<dim3(16,64,2), 256, 0, stream>>>(b_rm, bT);
    k3_gemm     <<<2048, 256, 0, stream>>>(aT, bT, sumT);
    k4_out      <<<4096, 256, 0, stream>>>(sumT, g_rm, Wfb, ln2w, ln2b, out);
}